// Round 10
// baseline (89.048 us; speedup 1.0000x reference)
//
#include <hip/hip_runtime.h>
#include <hip/hip_bf16.h>
#include <math.h>

#define LSEQ 512
#define DDIM 192

typedef __attribute__((ext_vector_type(8))) short s16x8;
typedef __attribute__((ext_vector_type(4))) float f32x4;
typedef unsigned short ushort_t;
typedef unsigned int uint_t;

#define MFMA16(a, b, c) __builtin_amdgcn_mfma_f32_16x16x32_bf16(a, b, c, 0, 0, 0)

__device__ __forceinline__ ushort_t f2b(float f) {
  union { float f; uint_t u; } v; v.f = f;
  uint_t r = (v.u + 0x7FFFu + ((v.u >> 16) & 1u)) >> 16;
  return (ushort_t)r;
}
__device__ __forceinline__ float b2f(ushort_t u) {
  union { uint_t u; float f; } v; v.u = ((uint_t)u) << 16;
  return v.f;
}
// packed f32x2 -> bf16x2 (RNE)
__device__ __forceinline__ uint_t cvtpk(float a, float b) {
  uint_t r;
  asm("v_cvt_pk_bf16_f32 %0, %1, %2" : "=v"(r) : "v"(a), "v"(b));
  return r;
}

typedef const __attribute__((address_space(1))) void g_void_t;
typedef __attribute__((address_space(3))) void lds_void_t;
__device__ __forceinline__ void load_lds16(const void* g, void* l) {
  __builtin_amdgcn_global_load_lds((g_void_t*)g, (lds_void_t*)l, 16, 0, 0);
}

// swizzled element index within a row (64-elem segments, 16B-block XOR row&7)
__device__ __forceinline__ size_t kswz(size_t row, int d) {
  return row * DDIM + (size_t)((d & 0x1C7) | ((((d >> 3) & 7) ^ ((int)row & 7)) << 3));
}

// ---------------- casts: x -> bf16 (swizzled) | W -> bf16^T (swizzled); zero flags ----------------
__global__ void cast_all(const float* __restrict__ x, const float* __restrict__ W,
                         ushort_t* __restrict__ xb, ushort_t* __restrict__ Wt,
                         uint_t* __restrict__ flags) {
  __shared__ float tile[32][33];
  const int id = blockIdx.x;
  if (id < 1024) {
    const int i = (id * 256 + threadIdx.x) * 8;
    const int row = i >> 9, k = i & 511;
    float4 a = *(const float4*)(x + i);
    float4 b = *(const float4*)(x + i + 4);
    uint4 o;
    o.x = (uint_t)f2b(a.x) | ((uint_t)f2b(a.y) << 16);
    o.y = (uint_t)f2b(a.z) | ((uint_t)f2b(a.w) << 16);
    o.z = (uint_t)f2b(b.x) | ((uint_t)f2b(b.y) << 16);
    o.w = (uint_t)f2b(b.z) | ((uint_t)f2b(b.w) << 16);
    const int dst = row * 512 + (k & 448) + (((((k >> 3) & 7) ^ (row & 7))) << 3);
    *(uint4*)(xb + dst) = o;
  } else {
    const int wid = id - 1024;
    if (wid == 0 && threadIdx.x < 64) flags[threadIdx.x] = 0u;  // visible at next dispatch
    const int tx = threadIdx.x & 31, ty = threadIdx.x >> 5;
    const int k0 = (wid & 15) * 32, n0 = (wid >> 4) * 32;
#pragma unroll
    for (int i = 0; i < 4; ++i)
      tile[ty + i * 8][tx] = W[(size_t)(k0 + ty + i * 8) * 1536 + n0 + tx];
    __syncthreads();
#pragma unroll
    for (int i = 0; i < 4; ++i) {
      const int n = n0 + ty + i * 8, k = k0 + tx;
      Wt[(size_t)n * 512 + (k & 448) + ((((k >> 3) & 7) ^ (n & 7)) << 3) + (k & 7)] =
          f2b(tile[tx][ty + i * 8]);
    }
  }
}

// ================= fused qkv + attn, per-(b,h) ready flags =================
// 512 blocks x 256 thr, 2 blocks/CU (64 KB LDS union) -> all co-resident.
// Blocks 0..383: one 128x128 qkv tile, then flag(+1) its two (b,h) groups.
// All blocks: attn tile (bh=bid&63, qg=bid>>6) after flags[bh]==12.
__global__ __launch_bounds__(256, 2) void fused(
    const ushort_t* __restrict__ xb, const ushort_t* __restrict__ Wt,
    const float* __restrict__ rr, const float* __restrict__ rw,
    ushort_t* __restrict__ Qt, ushort_t* __restrict__ Kt, ushort_t* __restrict__ Vt,
    const int* __restrict__ mask, float* __restrict__ out,
    uint_t* __restrict__ flags) {
  __shared__ __align__(16) char smem[65536];
  const int tid = threadIdx.x;
  const int bid = blockIdx.x;
  const int w = tid >> 6, lane = tid & 63, lo = lane & 15, hi = lane >> 4;

  // ---------------- PHASE 1: QKV GEMM (blocks 0..383) ----------------
  if (bid < 384) {
    ushort_t* ldsA = (ushort_t*)smem;            // [2][128*64] 32 KB
    ushort_t* ldsB = (ushort_t*)(smem + 32768);  // [2][128*64] 32 KB
    const int wm = w >> 1, wn = w & 1;
    const int mp = bid & 31, np = bid >> 5;  // 32 x 12
    const int m0 = mp * 128, n0 = np * 128;

    f32x4 acc[4][4];
    const f32x4 zero4 = {0.f, 0.f, 0.f, 0.f};
#pragma unroll
    for (int i = 0; i < 4; ++i)
#pragma unroll
      for (int j = 0; j < 4; ++j) acc[i][j] = zero4;

    const char* asrc = (const char*)xb + (size_t)m0 * 1024;
    const char* bsrc = (const char*)Wt + (size_t)n0 * 1024;

#define STAGE_QKV(buf, ks)                                                     \
  {                                                                            \
    char* la = (char*)ldsA + (buf) * 16384;                                    \
    char* lb = (char*)ldsB + (buf) * 16384;                                    \
    _Pragma("unroll") for (int it = 0; it < 4; ++it) {                         \
      const int X = it * 4096 + tid * 16;                                      \
      load_lds16(asrc + (size_t)(X >> 7) * 1024 + (ks) * 128 + (X & 127),      \
                 la + X);                                                      \
      load_lds16(bsrc + (size_t)(X >> 7) * 1024 + (ks) * 128 + (X & 127),      \
                 lb + X);                                                      \
    }                                                                          \
  }

    STAGE_QKV(0, 0);
    for (int ks = 0; ks < 8; ++ks) {
      const int cur = ks & 1;
      __syncthreads();
      if (ks < 7) STAGE_QKV(cur ^ 1, ks + 1);
      const char* Ab = (const char*)ldsA + cur * 16384;
      const char* Bb = (const char*)ldsB + cur * 16384;
#pragma unroll
      for (int kh = 0; kh < 2; ++kh) {
        const int sw = ((kh * 4 + hi) ^ (lo & 7)) << 4;
        s16x8 a[4], bf[4];
#pragma unroll
        for (int i = 0; i < 4; ++i)
          a[i] = *(const s16x8*)(Ab + (wm * 64 + i * 16 + lo) * 128 + sw);
#pragma unroll
        for (int j = 0; j < 4; ++j)
          bf[j] = *(const s16x8*)(Bb + (wn * 64 + j * 16 + lo) * 128 + sw);
#pragma unroll
        for (int i = 0; i < 4; ++i)
#pragma unroll
          for (int j = 0; j < 4; ++j)
            acc[i][j] = MFMA16(a[i], bf[j], acc[i][j]);
      }
    }

    const int gn0 = n0 + wn * 64;
    const int sect = gn0 >> 9;
    const int h = (gn0 >> 6) & 7;
    const int mrow0 = m0 + wm * 64;

    if (sect == 2) {
#pragma unroll
      for (int i = 0; i < 4; ++i) {
        const int m16 = mrow0 + i * 16;
        const int b = m16 >> 9;
        const int l0 = (m16 + hi * 4) & 511;
#pragma unroll
        for (int j = 0; j < 4; ++j) {
          ushort4 pk;
          pk.x = f2b(acc[i][j][0]); pk.y = f2b(acc[i][j][1]);
          pk.z = f2b(acc[i][j][2]); pk.w = f2b(acc[i][j][3]);
          *(ushort4*)&Vt[(((size_t)b * 8 + h) * 64 + j * 16 + lo) * 512 + l0] = pk;
        }
      }
    } else if (sect == 0) {
      // Q: 64 raw dims, (q+rr)*0.125; trig dims built in attn phase.
      float bias[4];
      int dcol[4];
#pragma unroll
      for (int j = 0; j < 4; ++j) {
        dcol[j] = (j < 2) ? j * 16 + lo : 32 + (j - 2) * 16 + lo;
        bias[j] = rr[h * 64 + dcol[j]];
      }
#pragma unroll
      for (int i = 0; i < 4; ++i)
#pragma unroll
        for (int r = 0; r < 4; ++r) {
          const int m = mrow0 + i * 16 + hi * 4 + r;
          const size_t row = ((size_t)(m >> 9) * 8 + h) * 512 + (m & 511);
#pragma unroll
          for (int j = 0; j < 4; ++j)
            Qt[row * 64 + dcol[j]] = f2b((acc[i][j][r] + bias[j]) * 0.125f);
        }
    } else {
#pragma unroll
      for (int p = 0; p < 2; ++p) {
        const int hf = p * 16 + lo;
        const float fq = __expf(-(float)hf * 0.29710775393472f);  // ln(1e4)/31
        float sfr, cfr;
        __sincosf(fq, &sfr, &cfr);
#pragma unroll
        for (int i = 0; i < 4; ++i)
#pragma unroll
          for (int r = 0; r < 4; ++r) {
            const int m = mrow0 + i * 16 + hi * 4 + r;
            const int l = m & 511;
            const size_t row = ((size_t)(m >> 9) * 8 + h) * 512 + l;
            float s0, c0;
            __sincosf((float)l * fq, &s0, &c0);
            const float s1 = s0 * cfr + c0 * sfr;
            const float c1 = c0 * cfr - s0 * sfr;
            const float ks_ = acc[i][p][r], kc_ = acc[i][p + 2][r];
            Kt[kswz(row, hf)]       = f2b(ks_);
            Kt[kswz(row, 32 + hf)]  = f2b(kc_);
            Kt[kswz(row, 64 + hf)]  = f2b(s1);
            Kt[kswz(row, 96 + hf)]  = f2b(c1);
            Kt[kswz(row, 128 + hf)] = f2b(ks_ * c0 + kc_ * s0);
            Kt[kswz(row, 160 + hf)] = f2b(kc_ * c0 - ks_ * s0);
          }
      }
    }

    __syncthreads();  // all waves' global writes complete (vmcnt drained)
    if (tid == 0) {
      __threadfence();  // agent-scope release of this block's Qt/Kt/Vt writes
      const int pb = (bid & 31) >> 2;
      const int ph0 = 2 * ((bid >> 5) & 3);
      __hip_atomic_fetch_add(&flags[pb * 8 + ph0], 1u, __ATOMIC_RELAXED,
                             __HIP_MEMORY_SCOPE_AGENT);
      __hip_atomic_fetch_add(&flags[pb * 8 + ph0 + 1], 1u, __ATOMIC_RELAXED,
                             __HIP_MEMORY_SCOPE_AGENT);
    }
  }

  // ---------------- PHASE 2: fused flash attention (all 512 blocks) ----------------
  {
    ushort_t* ldsK = (ushort_t*)smem;                             // [2][64*192] 48 KB
    ushort_t (*P)[16][72] = (ushort_t(*)[16][72])(smem + 49152);  // [4][16][72] 9 KB

    const int bh = bid & 63, qg = bid >> 6;  // same bh -> same XCD (bid%8 = bh%8)
    const int b = bh >> 3, h = bh & 7;
    const int q0 = qg * 64 + w * 16;
    const size_t qrow0 = (size_t)bh * LSEQ + q0;

    // wait for this (b,h)'s 12 producers (relaxed polls; one acquire fence on exit)
    if (tid == 0) {
      while (__hip_atomic_load(&flags[bh], __ATOMIC_RELAXED,
                               __HIP_MEMORY_SCOPE_AGENT) < 12u)
        __builtin_amdgcn_s_sleep(4);
      __threadfence();
    }
    __syncthreads();

    // Q̃ fragments: frags 0,1 from Qt; frags 2..5 (trig) computed in-register.
    s16x8 qf[6];
    {
      const ushort_t* qbase = Qt + (qrow0 + lo) * 64 + hi * 8;
      qf[0] = *(const s16x8*)(qbase);
      qf[1] = *(const s16x8*)(qbase + 32);
      const int l = q0 + lo;
#pragma unroll
      for (int j = 0; j < 8; ++j) {
        const int hfj = hi * 8 + j;
        const float fq = __expf(-(float)hfj * 0.29710775393472f);
        float s0, c0, s1, c1;
        __sincosf((float)l * fq, &s0, &c0);
        __sincosf((float)(l + 1) * fq, &s1, &c1);
        const float ds = 0.125f * (rw[h * 64 + hfj] - rr[h * 64 + hfj]);
        const float dc = 0.125f * (rw[h * 64 + 32 + hfj] - rr[h * 64 + 32 + hfj]);
        const float qs = b2f((ushort_t)qf[0][j]) + ds;
        const float qc = b2f((ushort_t)qf[1][j]) + dc;
        qf[2][j] = (short)f2b(qs * c0 + qc * s0);
        qf[3][j] = (short)f2b(qc * c0 - qs * s0);
        qf[4][j] = (short)f2b(0.125f * s1);
        qf[5][j] = (short)f2b(0.125f * c1);
      }
    }

    const f32x4 zero4 = {0.f, 0.f, 0.f, 0.f};
    f32x4 o[4];
#pragma unroll
    for (int j = 0; j < 4; ++j) o[j] = zero4;
    float mrun = -3.0e38f, lrun = 0.f;

    const char* ksrc = (const char*)(Kt + (size_t)bh * LSEQ * DDIM);
    const ushort_t* vbase = Vt + ((size_t)bh * 64 + lo) * 512 + hi * 8;

#pragma unroll
    for (int it = 0; it < 6; ++it) {
      const int X = it * 4096 + tid * 16;
      load_lds16(ksrc + X, (char*)ldsK + X);
    }

    for (int kt = 0; kt < 8; ++kt) {
      const int cur = kt & 1;

      const int mk = mask[b * LSEQ + kt * 64 + lane];
      s16x8 vbf[2][4];
#pragma unroll
      for (int kh = 0; kh < 2; ++kh)
#pragma unroll
        for (int j = 0; j < 4; ++j)
          vbf[kh][j] = *(const s16x8*)(vbase + (size_t)j * 16 * 512 + kt * 64 + kh * 32);

      // counted-vmcnt barrier (T4): 6 stage writes are the OLDEST outstanding
      // vmem ops; >=8 newer (vbf+mask) follow, so vmcnt(8) completes the tile.
      asm volatile("s_waitcnt vmcnt(8)" ::: "memory");
      __builtin_amdgcn_s_barrier();
      __builtin_amdgcn_sched_barrier(0);

      if (kt < 7) {
        const char* s = ksrc + (kt + 1) * 24576;
        char* d = (char*)ldsK + (cur ^ 1) * 24576;
#pragma unroll
        for (int it = 0; it < 6; ++it) {
          const int X = it * 4096 + tid * 16;
          load_lds16(s + X, d + X);
        }
      }

      f32x4 sf[4];
#pragma unroll
      for (int f = 0; f < 4; ++f) sf[f] = zero4;
      const char* kl = (const char*)ldsK + cur * 24576;
      __builtin_amdgcn_s_setprio(1);
#pragma unroll
      for (int ks = 0; ks < 6; ++ks) {
        const int swb = ((ks * 4 + hi) ^ (lo & 7)) << 4;
#pragma unroll
        for (int f = 0; f < 4; ++f) {
          s16x8 ka = *(const s16x8*)(kl + (f * 16 + lo) * 384 + swb);
          sf[f] = MFMA16(ka, qf[ks], sf[f]);
        }
      }
      __builtin_amdgcn_s_setprio(0);

      if (__ballot(mk == 0) != 0ull) {
#pragma unroll
        for (int f = 0; f < 4; ++f)
#pragma unroll
          for (int r = 0; r < 4; ++r)
            if (__shfl(mk, f * 16 + hi * 4 + r) == 0) sf[f][r] = -3.0e38f;
      }

      float tm = fmaxf(fmaxf(sf[0][0], sf[0][1]), fmaxf(sf[0][2], sf[0][3]));
#pragma unroll
      for (int f = 1; f < 4; ++f)
        tm = fmaxf(tm, fmaxf(fmaxf(sf[f][0], sf[f][1]), fmaxf(sf[f][2], sf[f][3])));
      tm = fmaxf(tm, __shfl_xor(tm, 16));
      tm = fmaxf(tm, __shfl_xor(tm, 32));

      if (!__all(tm - mrun <= 8.0f)) {  // defer-max (T13)
        const float mnew = fmaxf(mrun, tm);
        const float corr = __expf(mrun - mnew);
        lrun *= corr;
        mrun = mnew;
        float cq[4];
#pragma unroll
        for (int r = 0; r < 4; ++r) cq[r] = __shfl(corr, hi * 4 + r);
#pragma unroll
        for (int j = 0; j < 4; ++j)
#pragma unroll
          for (int r = 0; r < 4; ++r) o[j][r] *= cq[r];
      }

      float ts = 0.f;
#pragma unroll
      for (int f = 0; f < 4; ++f)
#pragma unroll
        for (int r = 0; r < 4; ++r) {
          sf[f][r] = __expf(sf[f][r] - mrun);
          ts += sf[f][r];
        }
      ts += __shfl_xor(ts, 16);
      ts += __shfl_xor(ts, 32);
      lrun += ts;

#pragma unroll
      for (int f = 0; f < 4; ++f) {
        uint2 u;
        u.x = cvtpk(sf[f][0], sf[f][1]);
        u.y = cvtpk(sf[f][2], sf[f][3]);
        *(uint2*)&P[w][lo][f * 16 + hi * 4] = u;
      }

      __builtin_amdgcn_s_setprio(1);
#pragma unroll
      for (int kh = 0; kh < 2; ++kh) {
        s16x8 pa = *(const s16x8*)&P[w][lo][kh * 32 + hi * 8];
#pragma unroll
        for (int j = 0; j < 4; ++j)
          o[j] = MFMA16(pa, vbf[kh][j], o[j]);
      }
      __builtin_amdgcn_s_setprio(0);
    }

    float lq[4];
#pragma unroll
    for (int r = 0; r < 4; ++r) lq[r] = 1.0f / __shfl(lrun, hi * 4 + r);
#pragma unroll
    for (int j = 0; j < 4; ++j)
#pragma unroll
      for (int r = 0; r < 4; ++r)
        out[((size_t)b * LSEQ + q0 + hi * 4 + r) * 512 + h * 64 + j * 16 + lo] =
            o[j][r] * lq[r];
  }
}

extern "C" void kernel_launch(void* const* d_in, const int* in_sizes, int n_in,
                              void* d_out, int out_size, void* d_ws, size_t ws_size,
                              hipStream_t stream) {
  const float* x    = (const float*)d_in[0];
  const int*   mask = (const int*)d_in[1];
  const float* W    = (const float*)d_in[2];
  const float* rr   = (const float*)d_in[3];
  const float* rw   = (const float*)d_in[4];
  float* out = (float*)d_out;

  // ws: xb 4M | Wt 1.5M | Qt 4M (64-dim) | Kt 12.6M | Vt 4M | flags 256B
  char* ws = (char*)d_ws;
  ushort_t* xb = (ushort_t*)(ws);
  ushort_t* Wt = (ushort_t*)(ws + 4194304);
  ushort_t* Qt = (ushort_t*)(ws + 5767168);
  ushort_t* Kt = (ushort_t*)(ws + 9961472);
  ushort_t* Vt = (ushort_t*)(ws + 22544384);
  uint_t* flags = (uint_t*)(ws + 26738688);

  cast_all<<<1792, 256, 0, stream>>>(x, W, xb, Wt, flags);
  fused<<<512, 256, 0, stream>>>(xb, Wt, rr, rw, Qt, Kt, Vt, mask, out, flags);
}

// Round 11
// 50.870 us; speedup vs baseline: 1.7505x; 1.7505x over previous
//
#include <hip/hip_runtime.h>
#include <hip/hip_bf16.h>
#include <math.h>

#define LSEQ 512
#define DDIM 192

typedef __attribute__((ext_vector_type(8))) short s16x8;
typedef __attribute__((ext_vector_type(4))) float f32x4;
typedef unsigned short ushort_t;
typedef unsigned int uint_t;

#define MFMA16(a, b, c) __builtin_amdgcn_mfma_f32_16x16x32_bf16(a, b, c, 0, 0, 0)

__device__ __forceinline__ ushort_t f2b(float f) {
  union { float f; uint_t u; } v; v.f = f;
  uint_t r = (v.u + 0x7FFFu + ((v.u >> 16) & 1u)) >> 16;
  return (ushort_t)r;
}
__device__ __forceinline__ float b2f(ushort_t u) {
  union { uint_t u; float f; } v; v.u = ((uint_t)u) << 16;
  return v.f;
}
// packed f32x2 -> bf16x2 (RNE)
__device__ __forceinline__ uint_t cvtpk(float a, float b) {
  uint_t r;
  asm("v_cvt_pk_bf16_f32 %0, %1, %2" : "=v"(r) : "v"(a), "v"(b));
  return r;
}

typedef const __attribute__((address_space(1))) void g_void_t;
typedef __attribute__((address_space(3))) void lds_void_t;
__device__ __forceinline__ void load_lds16(const void* g, void* l) {
  __builtin_amdgcn_global_load_lds((g_void_t*)g, (lds_void_t*)l, 16, 0, 0);
}

// swizzled element index within a row (64-elem segments, 16B-block XOR row&7)
__device__ __forceinline__ size_t kswz(size_t row, int d) {
  return row * DDIM + (size_t)((d & 0x1C7) | ((((d >> 3) & 7) ^ ((int)row & 7)) << 3));
}

// ---------------- fused casts: x -> bf16 (swizzled) | W -> bf16^T (swizzled) ----------------
__global__ void cast_all(const float* __restrict__ x, const float* __restrict__ W,
                         ushort_t* __restrict__ xb, ushort_t* __restrict__ Wt) {
  __shared__ float tile[32][33];
  const int id = blockIdx.x;
  if (id < 1024) {
    const int i = (id * 256 + threadIdx.x) * 8;
    const int row = i >> 9, k = i & 511;
    float4 a = *(const float4*)(x + i);
    float4 b = *(const float4*)(x + i + 4);
    uint4 o;
    o.x = (uint_t)f2b(a.x) | ((uint_t)f2b(a.y) << 16);
    o.y = (uint_t)f2b(a.z) | ((uint_t)f2b(a.w) << 16);
    o.z = (uint_t)f2b(b.x) | ((uint_t)f2b(b.y) << 16);
    o.w = (uint_t)f2b(b.z) | ((uint_t)f2b(b.w) << 16);
    const int dst = row * 512 + (k & 448) + (((((k >> 3) & 7) ^ (row & 7))) << 3);
    *(uint4*)(xb + dst) = o;
  } else {
    const int wid = id - 1024;
    const int tx = threadIdx.x & 31, ty = threadIdx.x >> 5;
    const int k0 = (wid & 15) * 32, n0 = (wid >> 4) * 32;
#pragma unroll
    for (int i = 0; i < 4; ++i)
      tile[ty + i * 8][tx] = W[(size_t)(k0 + ty + i * 8) * 1536 + n0 + tx];
    __syncthreads();
#pragma unroll
    for (int i = 0; i < 4; ++i) {
      const int n = n0 + ty + i * 8, k = k0 + tx;
      Wt[(size_t)n * 512 + (k & 448) + ((((k >> 3) & 7) ^ (n & 7)) << 3) + (k & 7)] =
          f2b(tile[tx][ty + i * 8]);
    }
  }
}

// ---------------- QKV GEMM: 64x128 tile, 4 waves (32x64 each), BK=64 ----------------
// 768 blocks = exactly 3/CU (48 KB LDS) -> balanced, no tail. Epilogue:
// Q (64-dim, biased+scaled), K̃ (192-dim w/ trig, swizzled), V^T.
__global__ __launch_bounds__(256, 3) void qkv_gemm(
    const ushort_t* __restrict__ xb, const ushort_t* __restrict__ Wt,
    const float* __restrict__ rr, const float* __restrict__ rw,
    ushort_t* __restrict__ Qt, ushort_t* __restrict__ Kt, ushort_t* __restrict__ Vt) {
  __shared__ __align__(16) ushort_t ldsA[2][64 * 64];    // 16 KB
  __shared__ __align__(16) ushort_t ldsB[2][128 * 64];   // 32 KB
  const int tid = threadIdx.x;
  const int w = tid >> 6, lane = tid & 63, lo = lane & 15, hi = lane >> 4;
  const int wm = w >> 1, wn = w & 1;
  const int id = blockIdx.x;
  const int mp = id & 63, np = id >> 6;  // 64 x 12
  const int m0 = mp * 64, n0 = np * 128;

  f32x4 acc[2][4];
  const f32x4 zero4 = {0.f, 0.f, 0.f, 0.f};
#pragma unroll
  for (int i = 0; i < 2; ++i)
#pragma unroll
    for (int j = 0; j < 4; ++j) acc[i][j] = zero4;

  const char* asrc = (const char*)xb + (size_t)m0 * 1024;
  const char* bsrc = (const char*)Wt + (size_t)n0 * 1024;

#define STAGE_QKV(buf, ks)                                                     \
  {                                                                            \
    char* la = (char*)&ldsA[buf][0];                                           \
    char* lb = (char*)&ldsB[buf][0];                                           \
    _Pragma("unroll") for (int it = 0; it < 2; ++it) {                         \
      const int X = it * 4096 + tid * 16;                                      \
      load_lds16(asrc + (size_t)(X >> 7) * 1024 + (ks) * 128 + (X & 127),      \
                 la + X);                                                      \
    }                                                                          \
    _Pragma("unroll") for (int it = 0; it < 4; ++it) {                         \
      const int X = it * 4096 + tid * 16;                                      \
      load_lds16(bsrc + (size_t)(X >> 7) * 1024 + (ks) * 128 + (X & 127),      \
                 lb + X);                                                      \
    }                                                                          \
  }

  STAGE_QKV(0, 0);
  for (int ks = 0; ks < 8; ++ks) {
    const int cur = ks & 1;
    __syncthreads();
    if (ks < 7) STAGE_QKV(cur ^ 1, ks + 1);
    const char* Ab = (const char*)&ldsA[cur][0];
    const char* Bb = (const char*)&ldsB[cur][0];
#pragma unroll
    for (int kh = 0; kh < 2; ++kh) {
      const int sw = ((kh * 4 + hi) ^ (lo & 7)) << 4;
      s16x8 a[2], bf[4];
#pragma unroll
      for (int i = 0; i < 2; ++i)
        a[i] = *(const s16x8*)(Ab + (wm * 32 + i * 16 + lo) * 128 + sw);
#pragma unroll
      for (int j = 0; j < 4; ++j)
        bf[j] = *(const s16x8*)(Bb + (wn * 64 + j * 16 + lo) * 128 + sw);
#pragma unroll
      for (int i = 0; i < 2; ++i)
#pragma unroll
        for (int j = 0; j < 4; ++j)
          acc[i][j] = MFMA16(a[i], bf[j], acc[i][j]);
    }
  }

  const int gn0 = n0 + wn * 64;
  const int sect = gn0 >> 9;
  const int h = (gn0 >> 6) & 7;
  const int mrow0 = m0 + wm * 32;

  if (sect == 2) {
#pragma unroll
    for (int i = 0; i < 2; ++i) {
      const int m16 = mrow0 + i * 16;
      const int b = m16 >> 9;
      const int l0 = (m16 + hi * 4) & 511;
#pragma unroll
      for (int j = 0; j < 4; ++j) {
        ushort4 pk;
        pk.x = f2b(acc[i][j][0]); pk.y = f2b(acc[i][j][1]);
        pk.z = f2b(acc[i][j][2]); pk.w = f2b(acc[i][j][3]);
        *(ushort4*)&Vt[(((size_t)b * 8 + h) * 64 + j * 16 + lo) * 512 + l0] = pk;
      }
    }
  } else if (sect == 0) {
    // Q: 64 raw dims, (q+rr)*0.125; trig dims built in attn kernel.
    float bias[4];
    int dcol[4];
#pragma unroll
    for (int j = 0; j < 4; ++j) {
      dcol[j] = (j < 2) ? j * 16 + lo : 32 + (j - 2) * 16 + lo;
      bias[j] = rr[h * 64 + dcol[j]];
    }
#pragma unroll
    for (int i = 0; i < 2; ++i)
#pragma unroll
      for (int r = 0; r < 4; ++r) {
        const int m = mrow0 + i * 16 + hi * 4 + r;
        const size_t row = ((size_t)(m >> 9) * 8 + h) * 512 + (m & 511);
#pragma unroll
        for (int j = 0; j < 4; ++j)
          Qt[row * 64 + dcol[j]] = f2b((acc[i][j][r] + bias[j]) * 0.125f);
      }
  } else {
#pragma unroll
    for (int p = 0; p < 2; ++p) {
      const int hf = p * 16 + lo;
      const float fq = __expf(-(float)hf * 0.29710775393472f);  // ln(1e4)/31
      float sfr, cfr;
      __sincosf(fq, &sfr, &cfr);
#pragma unroll
      for (int i = 0; i < 2; ++i)
#pragma unroll
        for (int r = 0; r < 4; ++r) {
          const int m = mrow0 + i * 16 + hi * 4 + r;
          const int l = m & 511;
          const size_t row = ((size_t)(m >> 9) * 8 + h) * 512 + l;
          float s0, c0;
          __sincosf((float)l * fq, &s0, &c0);
          const float s1 = s0 * cfr + c0 * sfr;
          const float c1 = c0 * cfr - s0 * sfr;
          const float ks_ = acc[i][p][r], kc_ = acc[i][p + 2][r];
          Kt[kswz(row, hf)]       = f2b(ks_);
          Kt[kswz(row, 32 + hf)]  = f2b(kc_);
          Kt[kswz(row, 64 + hf)]  = f2b(s1);
          Kt[kswz(row, 96 + hf)]  = f2b(c1);
          Kt[kswz(row, 128 + hf)] = f2b(ks_ * c0 + kc_ * s0);
          Kt[kswz(row, 160 + hf)] = f2b(kc_ * c0 - ks_ * s0);
        }
    }
  }
}

// ---------------- fused flash attention (R8 structure, unchanged) ----------------
__global__ __launch_bounds__(256, 2) void attn_kernel(
    const ushort_t* __restrict__ Qt, const ushort_t* __restrict__ Kt,
    const ushort_t* __restrict__ Vt, const int* __restrict__ mask,
    const float* __restrict__ rr, const float* __restrict__ rw,
    float* __restrict__ out) {
  __shared__ __align__(16) ushort_t ldsK[2][64 * DDIM];  // 2 x 24 KB
  __shared__ __align__(16) ushort_t P[4][16][72];        // per-wave P [q][k]

  const int tid = threadIdx.x;
  const int w = tid >> 6;
  const int lane = tid & 63, lo = lane & 15, hi = lane >> 4;
  const int id = blockIdx.x;
  const int bh = id & 63, qg = id >> 6;  // same bh -> same XCD (id%8 = bh%8)
  const int b = bh >> 3, h = bh & 7;
  const int q0 = qg * 64 + w * 16;
  const size_t qrow0 = (size_t)bh * LSEQ + q0;

  // Q̃ fragments: frags 0,1 from Qt; frags 2..5 (trig) computed in-register.
  s16x8 qf[6];
  {
    const ushort_t* qbase = Qt + (qrow0 + lo) * 64 + hi * 8;
    qf[0] = *(const s16x8*)(qbase);
    qf[1] = *(const s16x8*)(qbase + 32);
    const int l = q0 + lo;
#pragma unroll
    for (int j = 0; j < 8; ++j) {
      const int hfj = hi * 8 + j;
      const float fq = __expf(-(float)hfj * 0.29710775393472f);
      float s0, c0, s1, c1;
      __sincosf((float)l * fq, &s0, &c0);
      __sincosf((float)(l + 1) * fq, &s1, &c1);
      const float ds = 0.125f * (rw[h * 64 + hfj] - rr[h * 64 + hfj]);
      const float dc = 0.125f * (rw[h * 64 + 32 + hfj] - rr[h * 64 + 32 + hfj]);
      const float qs = b2f((ushort_t)qf[0][j]) + ds;
      const float qc = b2f((ushort_t)qf[1][j]) + dc;
      qf[2][j] = (short)f2b(qs * c0 + qc * s0);
      qf[3][j] = (short)f2b(qc * c0 - qs * s0);
      qf[4][j] = (short)f2b(0.125f * s1);
      qf[5][j] = (short)f2b(0.125f * c1);
    }
  }

  const f32x4 zero4 = {0.f, 0.f, 0.f, 0.f};
  f32x4 o[4];
#pragma unroll
  for (int j = 0; j < 4; ++j) o[j] = zero4;
  float mrun = -3.0e38f, lrun = 0.f;

  const char* ksrc = (const char*)(Kt + (size_t)bh * LSEQ * DDIM);
  const ushort_t* vbase = Vt + ((size_t)bh * 64 + lo) * 512 + hi * 8;

#pragma unroll
  for (int it = 0; it < 6; ++it) {
    const int X = it * 4096 + tid * 16;
    load_lds16(ksrc + X, (char*)&ldsK[0][0] + X);
  }

  for (int kt = 0; kt < 8; ++kt) {
    const int cur = kt & 1;

    const int mk = mask[b * LSEQ + kt * 64 + lane];
    s16x8 vbf[2][4];
#pragma unroll
    for (int kh = 0; kh < 2; ++kh)
#pragma unroll
      for (int j = 0; j < 4; ++j)
        vbf[kh][j] = *(const s16x8*)(vbase + (size_t)j * 16 * 512 + kt * 64 + kh * 32);

    // counted-vmcnt barrier (T4): 6 stage writes are the OLDEST outstanding
    // vmem ops; >=8 newer (vbf+mask) follow, so vmcnt(8) completes the tile.
    asm volatile("s_waitcnt vmcnt(8)" ::: "memory");
    __builtin_amdgcn_s_barrier();
    __builtin_amdgcn_sched_barrier(0);

    if (kt < 7) {
      const char* s = ksrc + (kt + 1) * 24576;
      char* d = (char*)&ldsK[cur ^ 1][0];
#pragma unroll
      for (int it = 0; it < 6; ++it) {
        const int X = it * 4096 + tid * 16;
        load_lds16(s + X, d + X);
      }
    }

    f32x4 sf[4];
#pragma unroll
    for (int f = 0; f < 4; ++f) sf[f] = zero4;
    const char* kl = (const char*)&ldsK[cur][0];
    __builtin_amdgcn_s_setprio(1);
#pragma unroll
    for (int ks = 0; ks < 6; ++ks) {
      const int swb = ((ks * 4 + hi) ^ (lo & 7)) << 4;
#pragma unroll
      for (int f = 0; f < 4; ++f) {
        s16x8 ka = *(const s16x8*)(kl + (f * 16 + lo) * 384 + swb);
        sf[f] = MFMA16(ka, qf[ks], sf[f]);
      }
    }
    __builtin_amdgcn_s_setprio(0);

    if (__ballot(mk == 0) != 0ull) {
#pragma unroll
      for (int f = 0; f < 4; ++f)
#pragma unroll
        for (int r = 0; r < 4; ++r)
          if (__shfl(mk, f * 16 + hi * 4 + r) == 0) sf[f][r] = -3.0e38f;
    }

    float tm = fmaxf(fmaxf(sf[0][0], sf[0][1]), fmaxf(sf[0][2], sf[0][3]));
#pragma unroll
    for (int f = 1; f < 4; ++f)
      tm = fmaxf(tm, fmaxf(fmaxf(sf[f][0], sf[f][1]), fmaxf(sf[f][2], sf[f][3])));
    tm = fmaxf(tm, __shfl_xor(tm, 16));
    tm = fmaxf(tm, __shfl_xor(tm, 32));

    if (!__all(tm - mrun <= 8.0f)) {  // defer-max (T13)
      const float mnew = fmaxf(mrun, tm);
      const float corr = __expf(mrun - mnew);
      lrun *= corr;
      mrun = mnew;
      float cq[4];
#pragma unroll
      for (int r = 0; r < 4; ++r) cq[r] = __shfl(corr, hi * 4 + r);
#pragma unroll
      for (int j = 0; j < 4; ++j)
#pragma unroll
        for (int r = 0; r < 4; ++r) o[j][r] *= cq[r];
    }

    float ts = 0.f;
#pragma unroll
    for (int f = 0; f < 4; ++f)
#pragma unroll
      for (int r = 0; r < 4; ++r) {
        sf[f][r] = __expf(sf[f][r] - mrun);
        ts += sf[f][r];
      }
    ts += __shfl_xor(ts, 16);
    ts += __shfl_xor(ts, 32);
    lrun += ts;

#pragma unroll
    for (int f = 0; f < 4; ++f) {
      uint2 u;
      u.x = cvtpk(sf[f][0], sf[f][1]);
      u.y = cvtpk(sf[f][2], sf[f][3]);
      *(uint2*)&P[w][lo][f * 16 + hi * 4] = u;
    }

    __builtin_amdgcn_s_setprio(1);
#pragma unroll
    for (int kh = 0; kh < 2; ++kh) {
      s16x8 pa = *(const s16x8*)&P[w][lo][kh * 32 + hi * 8];
#pragma unroll
      for (int j = 0; j < 4; ++j)
        o[j] = MFMA16(pa, vbf[kh][j], o[j]);
    }
    __builtin_amdgcn_s_setprio(0);
  }

  float lq[4];
#pragma unroll
  for (int r = 0; r < 4; ++r) lq[r] = 1.0f / __shfl(lrun, hi * 4 + r);
#pragma unroll
  for (int j = 0; j < 4; ++j)
#pragma unroll
    for (int r = 0; r < 4; ++r)
      out[((size_t)b * LSEQ + q0 + hi * 4 + r) * 512 + h * 64 + j * 16 + lo] =
          o[j][r] * lq[r];
}

extern "C" void kernel_launch(void* const* d_in, const int* in_sizes, int n_in,
                              void* d_out, int out_size, void* d_ws, size_t ws_size,
                              hipStream_t stream) {
  const float* x    = (const float*)d_in[0];
  const int*   mask = (const int*)d_in[1];
  const float* W    = (const float*)d_in[2];
  const float* rr   = (const float*)d_in[3];
  const float* rw   = (const float*)d_in[4];
  float* out = (float*)d_out;

  // ws: xb 4M | Wt 1.5M | Qt 4M (64-dim) | Kt 12.6M | Vt 4M
  char* ws = (char*)d_ws;
  ushort_t* xb = (ushort_t*)(ws);
  ushort_t* Wt = (ushort_t*)(ws + 4194304);
  ushort_t* Qt = (ushort_t*)(ws + 5767168);
  ushort_t* Kt = (ushort_t*)(ws + 9961472);
  ushort_t* Vt = (ushort_t*)(ws + 22544384);

  cast_all<<<1792, 256, 0, stream>>>(x, W, xb, Wt);
  qkv_gemm<<<768, 256, 0, stream>>>(xb, Wt, rr, rw, Qt, Kt, Vt);
  attn_kernel<<<512, 256, 0, stream>>>(Qt, Kt, Vt, mask, rr, rw, out);
}